// Round 8
// baseline (71.081 us; speedup 1.0000x reference)
//
#include <hip/hip_runtime.h>
#include <hip/hip_bf16.h>
#include <stdint.h>

#define DD 128
#define CC 16
#define NS 1600
#define QQ 32768
#define NBLK 64
#define QT 128  // q rows per main block

typedef __attribute__((ext_vector_type(8))) short short8;   // 8 bf16
typedef __attribute__((ext_vector_type(4))) short short4v;  // 4 bf16
typedef __attribute__((ext_vector_type(4))) float f32x4;

__device__ inline short f2bf(float x) {
  union { float f; uint32_t u; } v; v.f = x;
  uint32_t r = (v.u + 0x7FFFu + ((v.u >> 16) & 1u)) >> 16;  // RNE
  return (short)r;
}

__device__ inline uint32_t pk2bf(float lo, float hi) {
  __hip_bfloat162 h = __float22bfloat162_rn(make_float2(lo, hi));  // lo->low16
  union { __hip_bfloat162 h2; uint32_t u; } v; v.h2 = h;
  return v.u;
}

__device__ inline float bfbits2f(uint32_t hi16bits) {
  union { uint32_t u; float f; } v; v.u = hi16bits;
  return v.f;
}

// ---------------------------------------------------------------------------
// Kernel 1: fused prep. grid=320, block=256.
//  blocks [0,64):  per-block partial class sums.
//  blocks [64,320): q f32 -> bf16 conversion (qbf), coalesced.
// ---------------------------------------------------------------------------
__global__ __launch_bounds__(256) void prep_kernel(
    const float* __restrict__ sfi, const float* __restrict__ sf,
    const int* __restrict__ labels, const float* __restrict__ qf,
    float* __restrict__ partA, float* __restrict__ partB,
    float* __restrict__ pcnt, short* __restrict__ qbf) {
  const int t = threadIdx.x;

  if (blockIdx.x >= NBLK) {  // ---- q conversion: 128 rows per block ----
    const size_t cb = (size_t)(blockIdx.x - NBLK) * (128 * DD);
#pragma unroll
    for (int i = 0; i < 16; ++i) {
      const size_t off = cb + ((size_t)i * 256 + t) * 4;
      f32x4 f = *(const f32x4*)(qf + off);
      union { short4v s; uint32_t u[2]; } r;
      r.u[0] = pk2bf(f[0], f[1]);
      r.u[1] = pk2bf(f[2], f[3]);
      *(short4v*)(qbf + off) = r.s;
    }
    return;
  }

  // ---- centers partials ----
  __shared__ float accA[2][CC][DD];
  __shared__ float accB[2][CC][DD];
  __shared__ float cnt[2][CC];
  const int d = t & 127, s = t >> 7;
  for (int i = t; i < 2 * CC * DD; i += 256) {
    ((float*)accA)[i] = 0.f;
    ((float*)accB)[i] = 0.f;
  }
  if (t < 2 * CC) ((float*)cnt)[t] = 0.f;
  __syncthreads();

  const int base = blockIdx.x * (NS / NBLK);
  for (int i = s; i < NS / NBLK; i += 2) {
    const int r = base + i;
    const int lbl = labels[r];
    accA[s][lbl][d] += sfi[(size_t)r * DD + d];
    accB[s][lbl][d] += sf[(size_t)r * DD + d];
    if (d == 0) cnt[s][lbl] += 1.f;
  }
  __syncthreads();

  float* pa = partA + (size_t)blockIdx.x * (CC * DD);
  float* pb = partB + (size_t)blockIdx.x * (CC * DD);
  for (int i = t; i < CC * DD; i += 256) {
    pa[i] = ((float*)accA)[i] + ((float*)accA)[CC * DD + i];
    pb[i] = ((float*)accB)[i] + ((float*)accB)[CC * DD + i];
  }
  if (t < CC) pcnt[blockIdx.x * CC + t] = cnt[0][t] + cnt[1][t];
}

// ---------------------------------------------------------------------------
// Kernel 2: finalize centers + per-class weights, R2 swizzled LDS-image order.
// 16B unit p within class: row j = p>>4; physical slot (p&15) holds logical
// e-block eb = (p&15)^(j&7). Reader XORs the same way -> conflict-free b128.
// grid=16 (c), block=256.
// ---------------------------------------------------------------------------
__global__ __launch_bounds__(256) void build_wt_kernel(
    const float* __restrict__ W1, const float* __restrict__ partA,
    const float* __restrict__ partB, const float* __restrict__ pcnt,
    float* __restrict__ sg_out, short* __restrict__ WtTg) {
  __shared__ float sgc[DD], prc[DD];
  const int c = blockIdx.x, t = threadIdx.x;

  float cnt = 0.f;
  for (int b = 0; b < NBLK; ++b) cnt += pcnt[b * CC + c];
  cnt = fmaxf(cnt, 1.f);
  if (t < 128) {
    float a = 0.f;
    for (int b = 0; b < NBLK; ++b) a += partA[(size_t)b * (CC * DD) + c * DD + t];
    const float m = a / cnt;
    const float s = 1.f / (1.f + expf(-m));
    sgc[t] = s;
    sg_out[c * DD + t] = s;
  } else {
    const int d = t - 128;
    float a = 0.f;
    for (int b = 0; b < NBLK; ++b) a += partB[(size_t)b * (CC * DD) + c * DD + d];
    prc[d] = a / cnt;
  }
  __syncthreads();

  for (int it = 0; it < 8; ++it) {
    const int p = it * 256 + t;
    const int j = it * 16 + (t >> 4);
    const int eb = (t & 15) ^ ((t >> 4) & 7);  // j&7 == (t>>4)&7
    const int e0 = eb * 8;
    short8 r;
#pragma unroll
    for (int rr = 0; rr < 8; ++rr) {
      const int e = e0 + rr;
      float v = W1[e * DD + j] + sgc[e] * W1[(DD + e) * DD + j] +
                prc[e] * W1[2 * DD * DD + j];
      r[rr] = f2bf(v);
    }
    *(short8*)(WtTg + ((size_t)c * 2048 + p) * 8) = r;
  }
}

// ---------------------------------------------------------------------------
// Kernel 3: main. grid=256, block=1024 (16 waves, 4/SIMD), q-tile 128,
// 1 blk/CU (LDS 106KB). Wave (wq=w>>3, wj=w&7): j rows [wj*16,+16),
// q [wq*64,+64). W staged class-by-class into LDS dbuf via global_load_lds
// (32KB = 2 instr/thread); per-class compute (16 MFMA + fold) >> stage
// latency -> 1-deep prefetch covers. Fold lane-local (b1/W2 from LDS table)
// -> p_pln; REDUCE every 2 classes -> w_lds; fused agg epilogue.
// ---------------------------------------------------------------------------
__global__ __launch_bounds__(1024, 4) void main_kernel(
    const short* __restrict__ qbf, const short* __restrict__ WtTg,
    const float* __restrict__ b1, const float* __restrict__ W2,
    const float* __restrict__ b2, const float* __restrict__ sg,
    float* __restrict__ out) {
  __shared__ __align__(16) char Wl[2][32768];
  __shared__ float p_pln[2][16][65][4];  // [cls&1][wave][lane(pad)][qn]
  __shared__ float w_lds[QT][17];        // [q][c], padded
  __shared__ float b1_l[DD], w2_l[DD];

  const int tid = threadIdx.x;
  const int lane = tid & 63;
  const int w = tid >> 6;          // 0..15
  const int wq = w >> 3;           // 0..1
  const int wj = w & 7;            // 0..7
  const int l15 = lane & 15, l4 = lane >> 4;
  const int qbase = blockIdx.x * QT;

  if (tid < DD) { b1_l[tid] = b1[tid]; w2_l[tid] = W2[tid]; }
  const float b2s = b2[0];

  // ---- prologue: stage class 0 ----
  const char* gsrc = (const char*)WtTg;
#pragma unroll
  for (int i = 0; i < 2; ++i) {
    const int off = i * 16384 + tid * 16;
    __builtin_amdgcn_global_load_lds(
        (const __attribute__((address_space(1))) uint32_t*)(gsrc + off),
        (__attribute__((address_space(3))) uint32_t*)(&Wl[0][0] + off), 16, 0, 0);
  }

  // ---- B fragments: direct bf16 loads (overlap stage latency) ----
  short8 bq[4][4];
#pragma unroll
  for (int qn = 0; qn < 4; ++qn) {
    const short* qrow = qbf + (size_t)(qbase + wq * 64 + qn * 16 + l15) * DD;
#pragma unroll
    for (int kb = 0; kb < 4; ++kb)
      bq[qn][kb] = *(const short8*)(qrow + kb * 32 + l4 * 8);
  }

  // per-lane A-read byte offsets (XOR swizzle), reused every class
  int aoff[4];
#pragma unroll
  for (int kb = 0; kb < 4; ++kb)
    aoff[kb] = (wj * 16 + l15) * 256 + (((kb * 4 + l4) ^ (l15 & 7)) << 4);

  const f32x4* b1p = (const f32x4*)(b1_l + wj * 16 + l4 * 4);
  const f32x4* w2p = (const f32x4*)(w2_l + wj * 16 + l4 * 4);

  asm volatile("s_waitcnt vmcnt(0)" ::: "memory");
  __syncthreads();

  for (int c = 0; c < CC; ++c) {
    const int buf = c & 1;
    if (c + 1 < CC) {  // stage next class into other buffer
      const char* gc = gsrc + (size_t)(c + 1) * 32768;
#pragma unroll
      for (int i = 0; i < 2; ++i) {
        const int off = i * 16384 + tid * 16;
        __builtin_amdgcn_global_load_lds(
            (const __attribute__((address_space(1))) uint32_t*)(gc + off),
            (__attribute__((address_space(3))) uint32_t*)(&Wl[buf ^ 1][0] + off),
            16, 0, 0);
      }
    }

    // ---- compute class c from Wl[buf] ----
    {
      const char* wb = &Wl[buf][0];
      short8 A[4];
#pragma unroll
      for (int kb = 0; kb < 4; ++kb) A[kb] = *(const short8*)(wb + aoff[kb]);
      const f32x4 b1v = *b1p;
      const f32x4 w2v = *w2p;
      f32x4 pv;
#pragma unroll
      for (int qp = 0; qp < 2; ++qp) {
        f32x4 a0 = {0.f, 0.f, 0.f, 0.f}, a1 = {0.f, 0.f, 0.f, 0.f};
#pragma unroll
        for (int kb = 0; kb < 4; ++kb) {
          a0 = __builtin_amdgcn_mfma_f32_16x16x32_bf16(A[kb], bq[2 * qp][kb],
                                                       a0, 0, 0, 0);
          a1 = __builtin_amdgcn_mfma_f32_16x16x32_bf16(A[kb], bq[2 * qp + 1][kb],
                                                       a1, 0, 0, 0);
        }
        float p0 = 0.f, p1 = 0.f;
#pragma unroll
        for (int i = 0; i < 4; ++i) {
          p0 += fmaxf(a0[i] + b1v[i], 0.f) * w2v[i];
          p1 += fmaxf(a1[i] + b1v[i], 0.f) * w2v[i];
        }
        pv[2 * qp] = p0;
        pv[2 * qp + 1] = p1;
      }
      *(f32x4*)&p_pln[buf][w][lane][0] = pv;
    }

    asm volatile("s_waitcnt vmcnt(0)" ::: "memory");
    __syncthreads();

    if (c & 1) {  // REDUCE classes c-1, c
      if (tid < 256) {
        const int c1 = tid >> 7;         // 0..1
        const int ql = tid & 127;        // q local
        const int rq = ql >> 6;          // wq of this q
        const int qn = (ql >> 4) & 3;
        const int rl = ql & 15;
        float s = 0.f;
#pragma unroll
        for (int j8 = 0; j8 < 8; ++j8)
#pragma unroll
          for (int g = 0; g < 4; ++g)
            s += p_pln[c1][rq * 8 + j8][g * 16 + rl][qn];
        w_lds[ql][(c - 1) + c1] = 1.f / (1.f + __expf(-(s + b2s)));
      }
      __syncthreads();
    }
  }

  // ---- fused agg epilogue: wave w -> q-slots qi*16+w, lane -> e-pair ----
  {
    float2 sgv[16];
#pragma unroll
    for (int c = 0; c < 16; ++c)
      sgv[c] = *(const float2*)(sg + c * DD + 2 * lane);

#pragma unroll
    for (int qi = 0; qi < 8; ++qi) {
      const int ql = qi * 16 + w;
      const int q = qbase + ql;
      float Sv = 0.f, swx = 0.f, swy = 0.f;
#pragma unroll
      for (int c = 0; c < 16; ++c) {
        const float wc = w_lds[ql][c];  // wave-uniform broadcast
        Sv += wc;
        swx += wc * sgv[c].x;
        swy += wc * sgv[c].y;
      }
      const uint16_t* row = (const uint16_t*)(qbf + (size_t)q * DD);
      const uint32_t pair = *(const uint32_t*)(row + 2 * lane);
      const float q0 = bfbits2f(pair << 16);
      const float q1 = bfbits2f(pair & 0xFFFF0000u);
      const float qlo = bfbits2f((uint32_t)row[lane] << 16);
      const float qhi = bfbits2f((uint32_t)row[64 + lane] << 16);

      float* orow = out + (size_t)q * DD;
      orow[lane] = 0.5f * (q0 + q1) * Sv + qlo;
      orow[64 + lane] = 0.5f * (q0 * swx + q1 * swy) + qhi;
    }
  }
}

// ---------------------------------------------------------------------------
extern "C" void kernel_launch(void* const* d_in, const int* in_sizes, int n_in,
                              void* d_out, int out_size, void* d_ws, size_t ws_size,
                              hipStream_t stream) {
  const float* sfi = (const float*)d_in[0];
  const float* sf  = (const float*)d_in[1];
  const float* qf  = (const float*)d_in[2];
  const float* W1  = (const float*)d_in[3];
  const float* b1  = (const float*)d_in[4];
  const float* W2  = (const float*)d_in[5];
  const float* b2  = (const float*)d_in[6];
  const int* slab  = (const int*)d_in[7];
  float* out = (float*)d_out;

  float* sg    = (float*)d_ws;                    // 2048 f
  short* WtTg  = (short*)(sg + CC * DD);          // 262144 shorts (512 KB)
  float* partA = (float*)(WtTg + CC * DD * DD);   // 64*2048 f
  float* partB = partA + NBLK * CC * DD;          // 64*2048 f
  float* pcnt  = partB + NBLK * CC * DD;          // 64*16 f
  short* qbf   = (short*)(pcnt + NBLK * CC);      // QQ*DD shorts (8 MB)

  prep_kernel<<<NBLK + QQ / 128, 256, 0, stream>>>(sfi, sf, slab, qf, partA,
                                                   partB, pcnt, qbf);
  build_wt_kernel<<<CC, 256, 0, stream>>>(W1, partA, partB, pcnt, sg, WtTg);
  main_kernel<<<QQ / QT, 1024, 0, stream>>>(qbf, WtTg, b1, W2, b2, sg, out);
}